// Round 9
// baseline (2608.300 us; speedup 1.0000x reference)
//
#include <hip/hip_runtime.h>

#define S_LEN 512
#define HID   512
#define FEAT  26
#define NCLS  20
#define DRING 16

typedef short bf16x8 __attribute__((ext_vector_type(8)));
typedef float f32x4  __attribute__((ext_vector_type(4)));

__device__ __forceinline__ unsigned short f2bf(float f) {   // RNE
    unsigned u = __builtin_bit_cast(unsigned, f);
    unsigned r = (u + 0x7FFFu + ((u >> 16) & 1u)) >> 16;
    return (unsigned short)r;
}
__device__ __forceinline__ float sigm(float x) { return 1.f / (1.f + __expf(-x)); }
__device__ __forceinline__ float tanh_f(float x) {
    float xc = fminf(fmaxf(x, -15.f), 15.f);
    float t = __expf(-2.f * xc);
    return (1.f - t) / (1.f + t);
}

// 4 coherent 16B loads + drain (MLP staging path).
__device__ __forceinline__ void load4_coherent(const unsigned short* p,
                                               uint4& a0, uint4& a1, uint4& a2, uint4& a3) {
    asm volatile(
        "global_load_dwordx4 %0, %4, off sc0 sc1\n\t"
        "global_load_dwordx4 %1, %5, off sc0 sc1\n\t"
        "global_load_dwordx4 %2, %6, off sc0 sc1\n\t"
        "global_load_dwordx4 %3, %7, off sc0 sc1\n\t"
        "s_waitcnt vmcnt(0)"
        : "=&v"(a0), "=&v"(a1), "=&v"(a2), "=&v"(a3)
        : "v"(p), "v"(p + 8), "v"(p + 16), "v"(p + 24)
        : "memory");
}
// 16 coherent 16B loads (one base, 64B-offset ladder; offset BEFORE sc flags)
// + single drain: fills this lane's full h A-fragment set (kk=0..15) in MFMA layout.
__device__ __forceinline__ void loadA16_coherent(const unsigned short* p, uint4* a) {
    asm volatile(
        "global_load_dwordx4 %0, %16, off sc0 sc1\n\t"
        "global_load_dwordx4 %1, %16, off offset:64 sc0 sc1\n\t"
        "global_load_dwordx4 %2, %16, off offset:128 sc0 sc1\n\t"
        "global_load_dwordx4 %3, %16, off offset:192 sc0 sc1\n\t"
        "global_load_dwordx4 %4, %16, off offset:256 sc0 sc1\n\t"
        "global_load_dwordx4 %5, %16, off offset:320 sc0 sc1\n\t"
        "global_load_dwordx4 %6, %16, off offset:384 sc0 sc1\n\t"
        "global_load_dwordx4 %7, %16, off offset:448 sc0 sc1\n\t"
        "global_load_dwordx4 %8, %16, off offset:512 sc0 sc1\n\t"
        "global_load_dwordx4 %9, %16, off offset:576 sc0 sc1\n\t"
        "global_load_dwordx4 %10, %16, off offset:640 sc0 sc1\n\t"
        "global_load_dwordx4 %11, %16, off offset:704 sc0 sc1\n\t"
        "global_load_dwordx4 %12, %16, off offset:768 sc0 sc1\n\t"
        "global_load_dwordx4 %13, %16, off offset:832 sc0 sc1\n\t"
        "global_load_dwordx4 %14, %16, off offset:896 sc0 sc1\n\t"
        "global_load_dwordx4 %15, %16, off offset:960 sc0 sc1\n\t"
        "s_waitcnt vmcnt(0)"
        : "=&v"(a[0]), "=&v"(a[1]), "=&v"(a[2]), "=&v"(a[3]),
          "=&v"(a[4]), "=&v"(a[5]), "=&v"(a[6]), "=&v"(a[7]),
          "=&v"(a[8]), "=&v"(a[9]), "=&v"(a[10]), "=&v"(a[11]),
          "=&v"(a[12]), "=&v"(a[13]), "=&v"(a[14]), "=&v"(a[15])
        : "v"(p) : "memory");
}
// 4 coherent 2B h stores (one base, 1024B row ladder; offset BEFORE sc flags) + drain.
__device__ __forceinline__ void storeH4_coherent(unsigned short* p,
                                                 unsigned h0, unsigned h1,
                                                 unsigned h2, unsigned h3) {
    asm volatile(
        "global_store_short %0, %1, off sc0 sc1\n\t"
        "global_store_short %0, %2, off offset:1024 sc0 sc1\n\t"
        "global_store_short %0, %3, off offset:2048 sc0 sc1\n\t"
        "global_store_short %0, %4, off offset:3072 sc0 sc1\n\t"
        "s_waitcnt vmcnt(0)"
        :: "v"(p), "v"(h0), "v"(h1), "v"(h2), "v"(h3) : "memory");
}
// coherent dword store + drain.
__device__ __forceinline__ void store_coherent(unsigned short* p, unsigned d) {
    asm volatile(
        "global_store_dword %0, %1, off sc0 sc1\n\t"
        "s_waitcnt vmcnt(0)"
        :: "v"(p), "v"(d) : "memory");
}
// coherent dword store, no drain (flag publish).
__device__ __forceinline__ void store_u32_nowait(unsigned* p, unsigned d) {
    asm volatile("global_store_dword %0, %1, off sc0 sc1" :: "v"(p), "v"(d) : "memory");
}
// coherent dword load (poll).
__device__ __forceinline__ unsigned load_u32_coherent(const unsigned* p) {
    unsigned v;
    asm volatile("global_load_dword %0, %1, off sc0 sc1\n\ts_waitcnt vmcnt(0)"
                 : "=v"(v) : "v"(p) : "memory");
    return v;
}

// zero sync words, convert w1/w2 fp32 -> bf16
__global__ void prep_kernel(const float* __restrict__ w1, const float* __restrict__ w2,
                            unsigned short* __restrict__ w1b, unsigned short* __restrict__ w2b,
                            unsigned* __restrict__ syncw, int nclear) {
    int i = blockIdx.x * 256 + threadIdx.x;
    if (i < nclear) syncw[i] = 0u;
    if (i < 256 * 512) w1b[i] = f2bf(w1[i]);
    if (i < NCLS * 256) w2b[i] = f2bf(w2[i]);
}

// ============================================================================
// BIG-WS PATH: 256 wgs on 256 CUs (1 wg/CU).
// wg<128: LSTM, 16 clusters x 8 wgs, 64 units/wg. Wave w owns ALL 4 gates of
// units [U0+16w, U0+16w+16): gates computed in MFMA acc registers (no LDS),
// A-fragments loaded straight from hs into MFMA layout (no LDS staging).
// One barrier per step (pre-flag). wg>=128: MLP consumers.
// ============================================================================
__global__ __launch_bounds__(256, 1) void lstm_big_kernel(
    const float* __restrict__ x,
    const float* __restrict__ w_ih,
    const float* __restrict__ w_hh,
    const float* __restrict__ b_ih,
    const float* __restrict__ b_hh,
    const unsigned short* __restrict__ w1b,
    const float* __restrict__ b1,
    const unsigned short* __restrict__ w2b,
    const float* __restrict__ b2,
    float* __restrict__ out,
    unsigned short* __restrict__ hs,   // [16][S][16][HID] bf16
    unsigned* __restrict__ flags)      // [16][8] x 16-dword stride
{
    const int tid  = threadIdx.x;
    const int wave = tid >> 6;
    const int lane = tid & 63;
    const int quad = lane >> 4;
    const int l16  = lane & 15;
    const int wg   = blockIdx.x;

    __shared__ __align__(16) unsigned short At[16 * 552];   // MLP staging
    __shared__ __align__(16) unsigned short hid[16 * 264];  // MLP hidden
    __shared__ float lg[16 * 24];                           // MLP logits
    __shared__ unsigned rdy;                                // MLP epoch
    if (tid == 0) rdy = 0u;
    __syncthreads();

    if (wg < 128) {
        // =============== LSTM role ===============
        const int clust = wg >> 3;
        const int wic   = wg & 7;
        const int B0    = clust * 16;
        const int U0    = wic * 64;
        const int u     = U0 + wave * 16 + l16;    // this lane's hidden unit

        // persistent B fragments: bB[g][kk], rows g*512+u; kk 0..15 w_hh, 16 w_ih
        bf16x8 bB[4][17];
#pragma unroll
        for (int g = 0; g < 4; ++g) {
            const int row = g * 512 + u;
            const float* wrow = w_hh + (size_t)row * HID;
#pragma unroll
            for (int kk = 0; kk < 16; ++kk) {
                const float* p = wrow + kk * 32 + quad * 8;
                bf16x8 v;
#pragma unroll
                for (int j = 0; j < 8; ++j) v[j] = (short)f2bf(p[j]);
                bB[g][kk] = v;
            }
            const float* irow = w_ih + (size_t)row * FEAT;
            bf16x8 v;
#pragma unroll
            for (int j = 0; j < 8; ++j) {
                int ftr = quad * 8 + j;
                v[j] = (ftr < FEAT) ? (short)f2bf(irow[ftr]) : (short)0;
            }
            bB[g][16] = v;
        }
        float bias[4];
#pragma unroll
        for (int g = 0; g < 4; ++g) bias[g] = b_ih[g * 512 + u] + b_hh[g * 512 + u];

        float cst[4] = {0.f, 0.f, 0.f, 0.f};   // c-state: batch row quad*4+r, unit u

        unsigned short* hsc = hs + (size_t)clust * S_LEN * 16 * HID;
        unsigned* myflag = flags + (clust * 8 + wic) * 16;
        const unsigned* peer = flags + (clust * 8 + (lane & 7)) * 16;
        const float* xbase = x + (size_t)(B0 + l16) * S_LEN * FEAT;

        for (int t = 0; t < S_LEN; ++t) {
            // x fragment for A row l16 (plain cached loads; issued pre-poll)
            float xr[8];
#pragma unroll
            for (int j = 0; j < 8; ++j) {
                int c = quad * 8 + j;
                xr[j] = (c < FEAT) ? xbase[(size_t)t * FEAT + c] : 0.f;
            }
            if (t > 0) {      // every wave polls all 8 producer flags
                for (;;) {
                    unsigned v = load_u32_coherent(peer);
                    if (__ballot(v >= (unsigned)t) == ~0ull) break;
                }
            }
            bf16x8 ax;
#pragma unroll
            for (int j = 0; j < 8; ++j) ax[j] = (short)f2bf(xr[j]);

            f32x4 acc[4];
#pragma unroll
            for (int g = 0; g < 4; ++g) acc[g] = (f32x4){0.f, 0.f, 0.f, 0.f};
#pragma unroll
            for (int g = 0; g < 4; ++g)
                acc[g] = __builtin_amdgcn_mfma_f32_16x16x32_bf16(ax, bB[g][16], acc[g], 0, 0, 0);

            if (t > 0) {
                // A-fragments (h part) straight from hs into MFMA layout
                uint4 a[16];
                const unsigned short* abase =
                    hsc + ((size_t)(t - 1) * 16 + l16) * HID + quad * 8;
                loadA16_coherent(abase, a);
#pragma unroll
                for (int kk = 0; kk < 16; ++kk) {
                    bf16x8 af = __builtin_bit_cast(bf16x8, a[kk]);
#pragma unroll
                    for (int g = 0; g < 4; ++g)
                        acc[g] = __builtin_amdgcn_mfma_f32_16x16x32_bf16(af, bB[g][kk], acc[g], 0, 0, 0);
                }
            }

            // gates fully in-register: lane owns (batch quad*4+r, unit u)
            unsigned hv[4];
#pragma unroll
            for (int r = 0; r < 4; ++r) {
                float zi = acc[0][r] + bias[0];
                float zf = acc[1][r] + bias[1];
                float zg = acc[2][r] + bias[2];
                float zo = acc[3][r] + bias[3];
                float cn = sigm(zf) * cst[r] + sigm(zi) * tanh_f(zg);
                cst[r] = cn;
                hv[r] = (unsigned)f2bf(sigm(zo) * tanh_f(cn));
            }
            unsigned short* hp = hsc + ((size_t)t * 16 + quad * 4) * HID + u;
            storeH4_coherent(hp, hv[0], hv[1], hv[2], hv[3]);

            __syncthreads();             // all waves' h stores drained
            if (tid == 0) store_u32_nowait(myflag, (unsigned)(t + 1));
        }
    } else {
        // =============== MLP role ===============
        const int mwg  = wg - 128;
        const int mc   = mwg >> 3;
        const int m    = mwg & 7;
        const int B0   = mc * 16;
        const unsigned* peer = flags + (mc * 8 + (lane & 7)) * 16;
        const unsigned short* hsc = hs + (size_t)mc * S_LEN * 16 * HID;
        const int sm = tid >> 4;
        const int sc = tid & 15;

        for (int t = m; t < S_LEN; t += 8) {
            if (wave == 0) {
                for (;;) {
                    unsigned v = load_u32_coherent(peer);
                    if (__ballot(v >= (unsigned)(t + 1)) == ~0ull) break;
                    __builtin_amdgcn_s_sleep(8);
                }
                if (lane == 0)
                    __hip_atomic_store(&rdy, (unsigned)(t + 1), __ATOMIC_RELAXED,
                                       __HIP_MEMORY_SCOPE_WORKGROUP);
            } else {
                while (__hip_atomic_load(&rdy, __ATOMIC_RELAXED,
                                         __HIP_MEMORY_SCOPE_WORKGROUP) < (unsigned)(t + 1))
                    __builtin_amdgcn_s_sleep(8);
            }
            {
                const unsigned short* src = hsc + ((size_t)t * 16 + sm) * HID + sc * 32;
                unsigned short* dst = At + sm * 552 + sc * 32;
                uint4 a0, a1, a2, a3;
                load4_coherent(src, a0, a1, a2, a3);
                *(uint4*)(dst)      = a0;
                *(uint4*)(dst + 8)  = a1;
                *(uint4*)(dst + 16) = a2;
                *(uint4*)(dst + 24) = a3;
            }
            __syncthreads();

            f32x4 a1[4];
#pragma unroll
            for (int nt = 0; nt < 4; ++nt) a1[nt] = (f32x4){0.f, 0.f, 0.f, 0.f};
#pragma unroll
            for (int kk = 0; kk < 16; ++kk) {
                bf16x8 a = __builtin_bit_cast(
                    bf16x8, *(const uint4*)(At + l16 * 552 + kk * 32 + quad * 8));
#pragma unroll
                for (int nt = 0; nt < 4; ++nt) {
                    int n = wave * 64 + nt * 16 + l16;
                    bf16x8 b = __builtin_bit_cast(
                        bf16x8, *(const uint4*)(w1b + (size_t)n * 512 + kk * 32 + quad * 8));
                    a1[nt] = __builtin_amdgcn_mfma_f32_16x16x32_bf16(a, b, a1[nt], 0, 0, 0);
                }
            }
#pragma unroll
            for (int nt = 0; nt < 4; ++nt) {
                int n = wave * 64 + nt * 16 + l16;
                float bv = b1[n];
#pragma unroll
                for (int r = 0; r < 4; ++r)
                    hid[(quad * 4 + r) * 264 + n] = f2bf(fmaxf(a1[nt][r] + bv, 0.f));
            }
            __syncthreads();
            if (wave == 0) {
                f32x4 a2[2];
                a2[0] = (f32x4){0.f, 0.f, 0.f, 0.f};
                a2[1] = (f32x4){0.f, 0.f, 0.f, 0.f};
#pragma unroll
                for (int kk = 0; kk < 8; ++kk) {
                    bf16x8 a = __builtin_bit_cast(
                        bf16x8, *(const uint4*)(hid + l16 * 264 + kk * 32 + quad * 8));
#pragma unroll
                    for (int nt = 0; nt < 2; ++nt) {
                        int n = nt * 16 + l16;
                        bf16x8 b;
                        if (n < NCLS) {
                            b = __builtin_bit_cast(
                                bf16x8, *(const uint4*)(w2b + (size_t)n * 256 + kk * 32 + quad * 8));
                        } else {
                            uint4 z; z.x = z.y = z.z = z.w = 0u;
                            b = __builtin_bit_cast(bf16x8, z);
                        }
                        a2[nt] = __builtin_amdgcn_mfma_f32_16x16x32_bf16(a, b, a2[nt], 0, 0, 0);
                    }
                }
#pragma unroll
                for (int nt = 0; nt < 2; ++nt) {
                    int n = nt * 16 + l16;
                    if (n < NCLS) {
                        float bv = b2[n];
#pragma unroll
                        for (int r = 0; r < 4; ++r)
                            lg[(quad * 4 + r) * 24 + n] = a2[nt][r] + bv;
                    }
                }
            }
            __syncthreads();
            if (tid < 16) {
                float v[NCLS];
                float mx = -3.4e38f;
#pragma unroll
                for (int c = 0; c < NCLS; ++c) { v[c] = lg[tid * 24 + c]; mx = fmaxf(mx, v[c]); }
                float s = 0.f;
#pragma unroll
                for (int c = 0; c < NCLS; ++c) s += __expf(v[c] - mx);
                float lse = mx + __logf(s);
                float* orow = out + ((size_t)(B0 + tid) * S_LEN + t) * NCLS;
#pragma unroll
                for (int c = 0; c < NCLS; ++c) orow[c] = v[c] - lse;
            }
            __syncthreads();
        }
    }
}

// ============================================================================
// FALLBACK (small ws): round-6 kernel. 384 wgs, 16x16 LSTM + 16x8 MLP,
// 16-slot ring + done backpressure.
// ============================================================================
__global__ __launch_bounds__(256, 2) void lstm_fused_kernel(
    const float* __restrict__ x, const float* __restrict__ w_ih,
    const float* __restrict__ w_hh, const float* __restrict__ b_ih,
    const float* __restrict__ b_hh, const unsigned short* __restrict__ w1b,
    const float* __restrict__ b1, const unsigned short* __restrict__ w2b,
    const float* __restrict__ b2, float* __restrict__ out,
    unsigned short* __restrict__ hb, unsigned* __restrict__ flags,
    unsigned* __restrict__ done)
{
    const int tid  = threadIdx.x;
    const int wave = tid >> 6;
    const int lane = tid & 63;
    const int quad = lane >> 4;
    const int l16  = lane & 15;
    const int wg   = blockIdx.x;

    __shared__ __align__(16) unsigned short At[16 * 552];
    __shared__ float zb[16 * 132];
    __shared__ __align__(16) unsigned short hid[16 * 264];
    __shared__ float lg[16 * 24];
    __shared__ unsigned rdy;
    if (tid == 0) rdy = 0u;
    __syncthreads();

    if (wg < 256) {
        const int clust = (wg & 7) * 2 + (wg >= 128 ? 1 : 0);
        const int wic   = (wg >> 3) & 15;
        const int B0    = clust * 16;
        const int U0    = wic * 32;

        bf16x8 bB[2][17];
#pragma unroll
        for (int tl = 0; tl < 2; ++tl) {
            const int row = wave * 512 + U0 + tl * 16 + l16;
            const float* wrow = w_hh + (size_t)row * HID;
#pragma unroll
            for (int kk = 0; kk < 16; ++kk) {
                const float* p = wrow + kk * 32 + quad * 8;
                bf16x8 v;
#pragma unroll
                for (int j = 0; j < 8; ++j) v[j] = (short)f2bf(p[j]);
                bB[tl][kk] = v;
            }
            const float* irow = w_ih + (size_t)row * FEAT;
            bf16x8 v;
#pragma unroll
            for (int j = 0; j < 8; ++j) {
                int ftr = quad * 8 + j;
                v[j] = (ftr < FEAT) ? (short)f2bf(irow[ftr]) : (short)0;
            }
            bB[tl][16] = v;
        }

        const int gb = tid >> 4;
        const int gu = tid & 15;
        float bias[2][4];
#pragma unroll
        for (int uu = 0; uu < 2; ++uu)
#pragma unroll
            for (int g = 0; g < 4; ++g) {
                int r = g * 512 + U0 + 2 * gu + uu;
                bias[uu][g] = b_ih[r] + b_hh[r];
            }
        float cst[2] = {0.f, 0.f};

        const int sm = tid >> 4;
        const int sc = tid & 15;
        unsigned short* hbc = hb + (size_t)clust * DRING * 16 * HID;
        unsigned* myflag = flags + (clust * 16 + wic) * 16;
        const unsigned* peer = flags + (clust * 16 + (lane & 15)) * 16;

        for (int t = 0; t < S_LEN; ++t) {
            {
                unsigned pk = 0u;
                if (sc <= 12) {
                    float2 xv = *(const float2*)(x + ((size_t)(B0 + sm) * S_LEN + t) * FEAT + sc * 2);
                    pk = (unsigned)f2bf(xv.x) | ((unsigned)f2bf(xv.y) << 16);
                }
                *(unsigned*)(At + sm * 552 + 512 + sc * 2) = pk;
            }
            if (t > 0) {
                if (wave == 0) {
                    if (t >= DRING && lane == 0) {
                        const unsigned* dn = done + (clust * 8 + (t & 7)) * 16;
                        while (load_u32_coherent(dn) < (unsigned)(t - (DRING - 1)))
                            __builtin_amdgcn_s_sleep(8);
                    }
                    for (;;) {
                        unsigned v = load_u32_coherent(peer);
                        if (__ballot(v >= (unsigned)t) == ~0ull) break;
                        __builtin_amdgcn_s_sleep(1);
                    }
                    if (lane == 0)
                        __hip_atomic_store(&rdy, (unsigned)t, __ATOMIC_RELAXED,
                                           __HIP_MEMORY_SCOPE_WORKGROUP);
                } else {
                    while (__hip_atomic_load(&rdy, __ATOMIC_RELAXED,
                                             __HIP_MEMORY_SCOPE_WORKGROUP) < (unsigned)t)
                        __builtin_amdgcn_s_sleep(1);
                }
                const unsigned short* src =
                    hbc + ((t - 1) & (DRING - 1)) * 16 * HID + sm * HID + sc * 32;
                unsigned short* dst = At + sm * 552 + sc * 32;
                uint4 a0, a1, a2, a3;
                load4_coherent(src, a0, a1, a2, a3);
                *(uint4*)(dst)      = a0;
                *(uint4*)(dst + 8)  = a1;
                *(uint4*)(dst + 16) = a2;
                *(uint4*)(dst + 24) = a3;
            }
            __syncthreads();

            f32x4 acc0 = {0.f, 0.f, 0.f, 0.f};
            f32x4 acc1 = {0.f, 0.f, 0.f, 0.f};
            const unsigned short* arow = At + l16 * 552 + quad * 8;
            if (t > 0) {
#pragma unroll
                for (int kk = 0; kk < 17; ++kk) {
                    bf16x8 a = __builtin_bit_cast(bf16x8, *(const uint4*)(arow + kk * 32));
                    acc0 = __builtin_amdgcn_mfma_f32_16x16x32_bf16(a, bB[0][kk], acc0, 0, 0, 0);
                    acc1 = __builtin_amdgcn_mfma_f32_16x16x32_bf16(a, bB[1][kk], acc1, 0, 0, 0);
                }
            } else {
                bf16x8 a = __builtin_bit_cast(bf16x8, *(const uint4*)(arow + 16 * 32));
                acc0 = __builtin_amdgcn_mfma_f32_16x16x32_bf16(a, bB[0][16], acc0, 0, 0, 0);
                acc1 = __builtin_amdgcn_mfma_f32_16x16x32_bf16(a, bB[1][16], acc1, 0, 0, 0);
            }
#pragma unroll
            for (int r = 0; r < 4; ++r) {
                zb[(quad * 4 + r) * 132 + wave * 32 + l16]      = acc0[r];
                zb[(quad * 4 + r) * 132 + wave * 32 + 16 + l16] = acc1[r];
            }
            __syncthreads();

            {
                const float* zrow = zb + gb * 132;
                unsigned short hv2[2];
#pragma unroll
                for (int uu = 0; uu < 2; ++uu) {
                    int u = 2 * gu + uu;
                    float zi = zrow[u]      + bias[uu][0];
                    float zf = zrow[32 + u] + bias[uu][1];
                    float zg = zrow[64 + u] + bias[uu][2];
                    float zo = zrow[96 + u] + bias[uu][3];
                    float cn = sigm(zf) * cst[uu] + sigm(zi) * tanh_f(zg);
                    cst[uu] = cn;
                    hv2[uu] = f2bf(sigm(zo) * tanh_f(cn));
                }
                unsigned short* hp =
                    hbc + (t & (DRING - 1)) * 16 * HID + gb * HID + U0 + 2 * gu;
                store_coherent(hp, (unsigned)hv2[0] | ((unsigned)hv2[1] << 16));
            }
            __syncthreads();
            if (tid == 0) store_u32_nowait(myflag, (unsigned)(t + 1));
        }
    } else {
        const int mwg  = wg - 256;
        const int mc   = mwg >> 3;
        const int m    = mwg & 7;
        const int B0   = mc * 16;
        unsigned* mydone = done + (mc * 8 + m) * 16;
        const unsigned* peer = flags + (mc * 16 + (lane & 15)) * 16;
        const unsigned short* hbc = hb + (size_t)mc * DRING * 16 * HID;
        const int sm = tid >> 4;
        const int sc = tid & 15;

        for (int t = m; t < S_LEN; t += 8) {
            if (wave == 0) {
                for (;;) {
                    unsigned v = load_u32_coherent(peer);
                    if (__ballot(v >= (unsigned)(t + 1)) == ~0ull) break;
                    __builtin_amdgcn_s_sleep(8);
                }
                if (lane == 0)
                    __hip_atomic_store(&rdy, (unsigned)(t + 1), __ATOMIC_RELAXED,
                                       __HIP_MEMORY_SCOPE_WORKGROUP);
            } else {
                while (__hip_atomic_load(&rdy, __ATOMIC_RELAXED,
                                         __HIP_MEMORY_SCOPE_WORKGROUP) < (unsigned)(t + 1))
                    __builtin_amdgcn_s_sleep(8);
            }
            {
                const unsigned short* src =
                    hbc + (t & (DRING - 1)) * 16 * HID + sm * HID + sc * 32;
                unsigned short* dst = At + sm * 552 + sc * 32;
                uint4 a0, a1, a2, a3;
                load4_coherent(src, a0, a1, a2, a3);
                *(uint4*)(dst)      = a0;
                *(uint4*)(dst + 8)  = a1;
                *(uint4*)(dst + 16) = a2;
                *(uint4*)(dst + 24) = a3;
            }
            __syncthreads();
            if (tid == 0) store_u32_nowait(mydone, (unsigned)(t + 1));

            f32x4 a1[4];
#pragma unroll
            for (int nt = 0; nt < 4; ++nt) a1[nt] = (f32x4){0.f, 0.f, 0.f, 0.f};
#pragma unroll
            for (int kk = 0; kk < 16; ++kk) {
                bf16x8 a = __builtin_bit_cast(
                    bf16x8, *(const uint4*)(At + l16 * 552 + kk * 32 + quad * 8));
#pragma unroll
                for (int nt = 0; nt < 4; ++nt) {
                    int n = wave * 64 + nt * 16 + l16;
                    bf16x8 b = __builtin_bit_cast(
                        bf16x8, *(const uint4*)(w1b + (size_t)n * 512 + kk * 32 + quad * 8));
                    a1[nt] = __builtin_amdgcn_mfma_f32_16x16x32_bf16(a, b, a1[nt], 0, 0, 0);
                }
            }
#pragma unroll
            for (int nt = 0; nt < 4; ++nt) {
                int n = wave * 64 + nt * 16 + l16;
                float bv = b1[n];
#pragma unroll
                for (int r = 0; r < 4; ++r)
                    hid[(quad * 4 + r) * 264 + n] = f2bf(fmaxf(a1[nt][r] + bv, 0.f));
            }
            __syncthreads();
            if (wave == 0) {
                f32x4 a2[2];
                a2[0] = (f32x4){0.f, 0.f, 0.f, 0.f};
                a2[1] = (f32x4){0.f, 0.f, 0.f, 0.f};
#pragma unroll
                for (int kk = 0; kk < 8; ++kk) {
                    bf16x8 a = __builtin_bit_cast(
                        bf16x8, *(const uint4*)(hid + l16 * 264 + kk * 32 + quad * 8));
#pragma unroll
                    for (int nt = 0; nt < 2; ++nt) {
                        int n = nt * 16 + l16;
                        bf16x8 b;
                        if (n < NCLS) {
                            b = __builtin_bit_cast(
                                bf16x8, *(const uint4*)(w2b + (size_t)n * 256 + kk * 32 + quad * 8));
                        } else {
                            uint4 z; z.x = z.y = z.z = z.w = 0u;
                            b = __builtin_bit_cast(bf16x8, z);
                        }
                        a2[nt] = __builtin_amdgcn_mfma_f32_16x16x32_bf16(a, b, a2[nt], 0, 0, 0);
                    }
                }
#pragma unroll
                for (int nt = 0; nt < 2; ++nt) {
                    int n = nt * 16 + l16;
                    if (n < NCLS) {
                        float bv = b2[n];
#pragma unroll
                        for (int r = 0; r < 4; ++r)
                            lg[(quad * 4 + r) * 24 + n] = a2[nt][r] + bv;
                    }
                }
            }
            __syncthreads();
            if (tid < 16) {
                float v[NCLS];
                float mx = -3.4e38f;
#pragma unroll
                for (int c = 0; c < NCLS; ++c) { v[c] = lg[tid * 24 + c]; mx = fmaxf(mx, v[c]); }
                float s = 0.f;
#pragma unroll
                for (int c = 0; c < NCLS; ++c) s += __expf(v[c] - mx);
                float lse = mx + __logf(s);
                float* orow = out + ((size_t)(B0 + tid) * S_LEN + t) * NCLS;
#pragma unroll
                for (int c = 0; c < NCLS; ++c) orow[c] = v[c] - lse;
            }
            __syncthreads();
        }
    }
}

extern "C" void kernel_launch(void* const* d_in, const int* in_sizes, int n_in,
                              void* d_out, int out_size, void* d_ws, size_t ws_size,
                              hipStream_t stream) {
    const float* x    = (const float*)d_in[0];
    const float* w_ih = (const float*)d_in[1];
    const float* w_hh = (const float*)d_in[2];
    const float* b_ih = (const float*)d_in[3];
    const float* b_hh = (const float*)d_in[4];
    const float* w1   = (const float*)d_in[5];
    const float* b1   = (const float*)d_in[6];
    const float* w2   = (const float*)d_in[7];
    const float* b2   = (const float*)d_in[8];
    char* ws = (char*)d_ws;

    const size_t HS_BYTES = (size_t)16 * S_LEN * 16 * HID * 2;   // 128 MB
    const size_t NEED_BIG = HS_BYTES + 8192 + 262144 + 10240;

    if (ws_size >= NEED_BIG) {
        unsigned short* hsb   = (unsigned short*)ws;
        unsigned*       flags = (unsigned*)(ws + HS_BYTES);
        unsigned short* w1b   = (unsigned short*)(ws + HS_BYTES + 8192);
        unsigned short* w2b   = (unsigned short*)(ws + HS_BYTES + 8192 + 262144);
        prep_kernel<<<512, 256, 0, stream>>>(w1, w2, w1b, w2b, flags, 2048);
        lstm_big_kernel<<<256, 256, 0, stream>>>(x, w_ih, w_hh, b_ih, b_hh,
                                                 w1b, b1, w2b, b2,
                                                 (float*)d_out, hsb, flags);
    } else {
        unsigned short* hb    = (unsigned short*)ws;
        unsigned*       flags = (unsigned*)(ws + 4194304);
        unsigned*       done  = (unsigned*)(ws + 4194304 + 16384);
        unsigned short* w1b   = (unsigned short*)(ws + 4194304 + 16384 + 8192);
        unsigned short* w2b   = (unsigned short*)(ws + 4194304 + 16384 + 8192 + 262144);
        prep_kernel<<<512, 256, 0, stream>>>(w1, w2, w1b, w2b, flags, 6144);
        lstm_fused_kernel<<<384, 256, 0, stream>>>(x, w_ih, w_hh, b_ih, b_hh,
                                                   w1b, b1, w2b, b2,
                                                   (float*)d_out, hb, flags, done);
    }
}